// Round 19
// baseline (189.147 us; speedup 1.0000x reference)
//
#include <hip/hip_runtime.h>
#include <math.h>
#include <stdint.h>

// ---------------- dims ----------------
#define BETA 0.9f
#define THR 1.0f
#define T_STEPS 50
#define BN_EPS 1e-5f

#define NITEM 64          // 2 inputs x 32 batch
#define C1 16
#define L1 1981           // conv1 out length
#define P4 495            // pooled length
#define C2 32
#define L2 493            // conv2 out length
#define L2PAD 496
#define KTOT 15872        // C2*L2PAD (padded flat dim)
#define KREAL 15776       // C2*L2
#define NFC 250
#define NPAD 256
#define KSPLIT 16
#define KRANGE 992        // KTOT/KSPLIT
#define KSTEPS 31         // KRANGE/32
#define NKTILE 496        // KTOT/32
#define MROWS 3200        // T_STEPS*NITEM
#define TSLICE 1015808    // KTOT*64 bytes per t (blocked spk2 slice)

// ---------------- workspace layout (bytes) ----------------
#define OFF_CUR1 0UL
#define OFF_POOL 8126464UL            // pooledT
#define OFF_SPK2 34340864UL           // spk2 blocked = 50*TSLICE
#define OFF_WT   85131264UL           // wTf
// cur1 region is pure scratch: cur3 at +16384 (3.3 MB, L2-resident accumulate target)
#define OFF_CUR3 16384UL

typedef __attribute__((ext_vector_type(8))) short bf16x8;
typedef __attribute__((ext_vector_type(4))) float f32x4;

__device__ __forceinline__ uint32_t f32_to_bf16_rne(float f) {
  uint32_t u = __float_as_uint(f);
  return (u + 0x7FFFu + ((u >> 16) & 1u)) >> 16;
}

// spike bytes (bit0) -> 8 bf16 {0,1} in PERMUTED k-order [0,2,1,3,4,6,5,7]
// (B operands are packed in the same order, so the MFMA dot product is unchanged)
__device__ __forceinline__ bf16x8 frag_from_bytes(uint2 a) {
  union { uint32_t u[4]; bf16x8 v; } c;
  c.u[0] = (a.x & 0x00010001u) * 0x3F80u;          // k0,k2
  c.u[1] = ((a.x >> 8) & 0x00010001u) * 0x3F80u;   // k1,k3
  c.u[2] = (a.y & 0x00010001u) * 0x3F80u;          // k4,k6
  c.u[3] = ((a.y >> 8) & 0x00010001u) * 0x3F80u;   // k5,k7
  return c.v;
}

// ---------------- K_pre: MERGED independent prep ----------------
// blocks [0, 496): k_wt  -- fc1w -> wTf fragment-ready bf16 hi/lo (permuted k-pairs)
// blocks [496, 1008): conv1+BN1 (LDS) + LIF1 + maxpool4 -> pooledT (x hoisted to registers)
__global__ __launch_bounds__(256) void k_pre(const float* __restrict__ fc1w,
                                             uint8_t* __restrict__ wTf,
                                             const float* __restrict__ x1, const float* __restrict__ x2,
                                             const float* __restrict__ c1w, const float* __restrict__ c1b,
                                             const float* __restrict__ g, const float* __restrict__ bb,
                                             const float* __restrict__ mn, const float* __restrict__ vr,
                                             uint8_t* __restrict__ pooledT) {
  __shared__ __align__(16) union SM {
    float ftile[256][33];                                  // wt branch (33.8 KB)
    struct { float xs[1104]; float cur_l[16][260]; } c;    // conv branch (21.1 KB)
  } sm;
  int bid = blockIdx.x;
  int tid = threadIdx.x;

  if (bid < NKTILE) {
    // ----- k_wt body (kt = bid) -----
    int kt = bid;
    {
      int kk = tid & 31;
      int r8 = tid >> 5;
      int k = kt * 32 + kk;
      int oc = k / L2PAD;
      int pos = k - oc * L2PAD;
      bool kvalid = (pos < L2);
      size_t src = (size_t)oc * L2 + pos;
#pragma unroll
      for (int p = 0; p < 32; ++p) {
        int n = p * 8 + r8;
        float w = 0.f;
        if (kvalid && n < NFC) w = fc1w[(size_t)n * KREAL + src];
        sm.ftile[n][kk] = w;
      }
    }
    __syncthreads();
    int n = tid;
    int wv = n >> 6, ni = (n >> 4) & 3, r16 = n & 15;
    uint32_t h16[32], l16[32];
#pragma unroll
    for (int kl = 0; kl < 32; ++kl) {
      float w = sm.ftile[n][kl];
      uint32_t hb = f32_to_bf16_rne(w);
      float hf = __uint_as_float(hb << 16);
      h16[kl] = hb;
      l16[kl] = f32_to_bf16_rne(w - hf);
    }
    uint8_t* tb = wTf + (size_t)kt * 32768 + wv * 8192 + ni * 2048;
#pragma unroll
    for (int gq = 0; gq < 4; ++gq) {
      int b = gq * 8;
      uint4 h;
      h.x = h16[b + 0] | (h16[b + 2] << 16);
      h.y = h16[b + 1] | (h16[b + 3] << 16);
      h.z = h16[b + 4] | (h16[b + 6] << 16);
      h.w = h16[b + 5] | (h16[b + 7] << 16);
      *reinterpret_cast<uint4*>(tb + (gq * 16 + r16) * 16) = h;
      uint4 l;
      l.x = l16[b + 0] | (l16[b + 2] << 16);
      l.y = l16[b + 1] | (l16[b + 3] << 16);
      l.z = l16[b + 4] | (l16[b + 6] << 16);
      l.w = l16[b + 5] | (l16[b + 7] << 16);
      *reinterpret_cast<uint4*>(tb + 1024 + (gq * 16 + r16) * 16) = l;
    }
  } else {
    // ----- conv1+LIF1 body -----
    int b = bid - NKTILE;
    int pc = b & 7;
    int item = b >> 3;
    const float* x = (item < 32 ? x1 : x2) + (item & 31) * 8000;
    int xoff = pc * 1024;
    for (int i = tid; i < 1100; i += 256) {
      int gi = xoff + i;
      sm.c.xs[i] = (gi < 8000) ? x[gi] : 0.f;
    }
    __syncthreads();
    const float4* xs4 = reinterpret_cast<const float4*>(sm.c.xs);
    float4 xv[20];
#pragma unroll
    for (int k4 = 0; k4 < 20; ++k4) xv[k4] = xs4[tid + k4];   // channel-invariant: load ONCE
    for (int c = 0; c < C1; ++c) {
      float s = g[c] / sqrtf(vr[c] + BN_EPS);
      float sh = (c1b[c] - mn[c]) * s + bb[c];
      const float4* w4 = reinterpret_cast<const float4*>(c1w + c * 80);
      float acc = 0.f;
#pragma unroll
      for (int k4 = 0; k4 < 20; ++k4) {
        float4 wv4 = w4[k4];
        acc += wv4.x * xv[k4].x; acc += wv4.y * xv[k4].y;
        acc += wv4.z * xv[k4].z; acc += wv4.w * xv[k4].w;
      }
      sm.c.cur_l[c][tid] = acc * s + sh;
    }
    __syncthreads();
    int gq = tid & 3;
    int p4l = tid >> 2;
    int p4 = pc * 64 + p4l;
    if (p4 >= P4) return;
    float4 cv[4];
#pragma unroll
    for (int j = 0; j < 4; ++j)
      cv[j] = *reinterpret_cast<const float4*>(&sm.c.cur_l[gq * 4 + j][4 * p4l]);
    float m[4][4];
#pragma unroll
    for (int j = 0; j < 4; ++j)
#pragma unroll
      for (int r = 0; r < 4; ++r) m[j][r] = 0.f;
    uint32_t* out = reinterpret_cast<uint32_t*>(pooledT + ((size_t)item * 50 * 512 + p4) * 16 + gq * 4);
    for (int t = 0; t < T_STEPS; ++t) {
      uint32_t pk = 0;
#pragma unroll
      for (int j = 0; j < 4; ++j) {
        int s = 0;
#pragma unroll
        for (int r = 0; r < 4; ++r) {
          float rst = (m[j][r] > THR) ? 1.f : 0.f;
          float cvv = (r == 0) ? cv[j].x : (r == 1) ? cv[j].y : (r == 2) ? cv[j].z : cv[j].w;
          m[j][r] = BETA * m[j][r] + cvv - rst;
          s |= (m[j][r] > THR);
        }
        pk |= ((uint32_t)s) << (8 * j);
      }
      out[t * 2048] = pk;
    }
  }
}

// ---------------- K4: conv2 via MFMA + LIF2, inline weight frags -> spk2 BLOCKED [t][kchunk][item][32B] ----------------
__global__ __launch_bounds__(256) void k_conv2(const uint8_t* __restrict__ pooledT,
                                               const float* __restrict__ c2w, const float* __restrict__ c2b,
                                               const float* __restrict__ g, const float* __restrict__ bb,
                                               const float* __restrict__ mn, const float* __restrict__ vr,
                                               uint32_t* __restrict__ spk2) {
  int item = blockIdx.y;
  int pt = blockIdx.x;
  int tid = threadIdx.x;
  int lane = tid & 63, wv = tid >> 6;
  int r16 = lane & 15, kg = lane >> 4;
  bf16x8 bw[2][2][2];
  float sh[2];
#pragma unroll
  for (int nt = 0; nt < 2; ++nt) {
    int oc = nt * 16 + r16;
    float s2 = g[oc] * rsqrtf(vr[oc] + BN_EPS);
    sh[nt] = (c2b[oc] - mn[oc]) * s2 + bb[oc];
#pragma unroll
    for (int kt = 0; kt < 2; ++kt) {
      uint32_t h[8], l[8];
#pragma unroll
      for (int j = 0; j < 8; ++j) {
        int k = kt * 32 + kg * 8 + j;
        int tap = k >> 4, ic = k & 15;
        float raw = (tap < 3) ? c2w[oc * 48 + ic * 3 + tap] * s2 : 0.f;
        uint32_t hb = f32_to_bf16_rne(raw);
        float hf = __uint_as_float(hb << 16);
        h[j] = hb;
        l[j] = f32_to_bf16_rne(raw - hf);
      }
      union { uint32_t u[4]; bf16x8 v; } ch_, cl_;
      ch_.u[0] = h[0] | (h[2] << 16); ch_.u[1] = h[1] | (h[3] << 16);
      ch_.u[2] = h[4] | (h[6] << 16); ch_.u[3] = h[5] | (h[7] << 16);
      cl_.u[0] = l[0] | (l[2] << 16); cl_.u[1] = l[1] | (l[3] << 16);
      cl_.u[2] = l[4] | (l[6] << 16); cl_.u[3] = l[5] | (l[7] << 16);
      bw[nt][kt][0] = ch_.v;
      bw[nt][kt][1] = cl_.v;
    }
  }
  const uint8_t* base = pooledT + (size_t)item * 50 * 8192;
  int rowA = pt * 64 + wv * 16 + r16;
  size_t off0 = (size_t)(rowA + (kg >> 1)) * 16 + 8 * (kg & 1);   // taps 0/1
  size_t off1 = (size_t)(rowA + 2) * 16 + 8 * (kg & 1);           // tap 2 (+pad)
  uint2 na0 = *reinterpret_cast<const uint2*>(base + off0);
  uint2 na1 = *reinterpret_cast<const uint2*>(base + off1);
  float mem[2][4] = {{0.f, 0.f, 0.f, 0.f}, {0.f, 0.f, 0.f, 0.f}};
  int pos_base = pt * 64 + wv * 16 + kg * 4;
  bool dostore = pos_base < L2PAD;
  int k0a = r16 * L2PAD + pos_base;
  int k0b = (16 + r16) * L2PAD + pos_base;
  uint32_t sidx0 = (uint32_t)(k0a >> 5) * 512u + (uint32_t)item * 8u + ((uint32_t)(k0a >> 2) & 7u);
  uint32_t sidx1 = (uint32_t)(k0b >> 5) * 512u + (uint32_t)item * 8u + ((uint32_t)(k0b >> 2) & 7u);
  for (int t = 0; t < T_STEPS; ++t) {
    uint2 a0 = na0, a1 = na1;
    const uint8_t* nb = base + (size_t)((t + 1 < T_STEPS) ? t + 1 : t) * 8192;
    na0 = *reinterpret_cast<const uint2*>(nb + off0);
    na1 = *reinterpret_cast<const uint2*>(nb + off1);
    bf16x8 af0 = frag_from_bytes(a0);
    bf16x8 af1 = frag_from_bytes(a1);
    uint32_t st[2];
#pragma unroll
    for (int nt = 0; nt < 2; ++nt) {
      f32x4 acc = (f32x4){0.f, 0.f, 0.f, 0.f};
      acc = __builtin_amdgcn_mfma_f32_16x16x32_bf16(af0, bw[nt][0][0], acc, 0, 0, 0);
      acc = __builtin_amdgcn_mfma_f32_16x16x32_bf16(af1, bw[nt][1][0], acc, 0, 0, 0);
      acc = __builtin_amdgcn_mfma_f32_16x16x32_bf16(af0, bw[nt][0][1], acc, 0, 0, 0);
      acc = __builtin_amdgcn_mfma_f32_16x16x32_bf16(af1, bw[nt][1][1], acc, 0, 0, 0);
      uint32_t packed = 0;
#pragma unroll
      for (int r = 0; r < 4; ++r) {
        float rst = (mem[nt][r] > THR) ? 1.f : 0.f;
        mem[nt][r] = BETA * mem[nt][r] + (acc[r] + sh[nt]) - rst;
        packed |= (mem[nt][r] > THR ? 1u : 0u) << (8 * r);
      }
      st[nt] = packed;
    }
    if (dostore) {
      uint32_t tb = (uint32_t)t * (TSLICE / 4);
      spk2[tb + sidx0] = st[0];
      spk2[tb + sidx1] = st[1];
    }
  }
}

// ---------------- K5: fc1 MFMA GEMM, LDS-free, blocked-A, M=128 via 8 waves; ATOMIC accumulate -> cur3 ----------------
// cur3 (3.3 MB) is L2-resident: removes the 52 MB part write + 52 MB k_red read HBM round-trip.
__global__ __launch_bounds__(512) void k_fc1(const uint8_t* __restrict__ spk2,
                                             const uint8_t* __restrict__ wTf,
                                             float* __restrict__ cur3) {
  int ks = blockIdx.x;       // 0..15
  int mt = blockIdx.y;       // 0..24
  int tid = threadIdx.x;
  int lane = tid & 63, w8 = tid >> 6;
  int wv = w8 & 3, mg = w8 >> 2;
  int r16 = lane & 15, kg = lane >> 4;
  int t = mt * 2 + mg;

  f32x4 acc[4][4];
#pragma unroll
  for (int mi = 0; mi < 4; ++mi)
#pragma unroll
    for (int ni = 0; ni < 4; ++ni) acc[mi][ni] = (f32x4){0.f, 0.f, 0.f, 0.f};

  const uint8_t* abase = spk2 + (size_t)t * TSLICE + (size_t)(ks * KSTEPS) * 2048 + r16 * 32 + kg * 8;
  const uint8_t* bbase = wTf + (size_t)ks * KSTEPS * 32768 + wv * 8192 + lane * 16;

  for (int ch = 0; ch < KSTEPS; ++ch) {
    uint2 a[4];
#pragma unroll
    for (int mi = 0; mi < 4; ++mi)
      a[mi] = *reinterpret_cast<const uint2*>(abase + (size_t)ch * 2048 + mi * 512);
    bf16x8 bfr[4][2];
#pragma unroll
    for (int ni = 0; ni < 4; ++ni)
#pragma unroll
      for (int sel = 0; sel < 2; ++sel)
        bfr[ni][sel] = *reinterpret_cast<const bf16x8*>(bbase + (size_t)ch * 32768 + ni * 2048 + sel * 1024);
    bf16x8 af[4];
#pragma unroll
    for (int mi = 0; mi < 4; ++mi) af[mi] = frag_from_bytes(a[mi]);
#pragma unroll
    for (int ni = 0; ni < 4; ++ni)
#pragma unroll
      for (int mi = 0; mi < 4; ++mi) {
        acc[mi][ni] = __builtin_amdgcn_mfma_f32_16x16x32_bf16(af[mi], bfr[ni][0], acc[mi][ni], 0, 0, 0);
        acc[mi][ni] = __builtin_amdgcn_mfma_f32_16x16x32_bf16(af[mi], bfr[ni][1], acc[mi][ni], 0, 0, 0);
      }
  }
  int colb = wv * 64 + r16;
  int rowb = t * 64 + kg * 4;
#pragma unroll
  for (int mi = 0; mi < 4; ++mi)
#pragma unroll
    for (int ni = 0; ni < 4; ++ni) {
      float* pp = cur3 + (size_t)(rowb + mi * 16) * NPAD + colb + ni * 16;
#pragma unroll
      for (int r = 0; r < 4; ++r) atomicAdd(&pp[r * NPAD], acc[mi][ni][r]);
    }
}

// ---------------- K6b: FUSED LIF3 + head GEMM + L2 normalize -> d_out ----------------
__global__ __launch_bounds__(256) void k_tail(const float* __restrict__ cur3,
                                              const float* __restrict__ fc1b,
                                              const float* __restrict__ fcsw,
                                              const float* __restrict__ fcsb,
                                              float* __restrict__ dout) {
  __shared__ float cr[500];
  __shared__ float red[2];
  int item = blockIdx.x;
  int n = threadIdx.x;
  if (n < NFC) {
    float bias = fc1b[n];
    float sv[T_STEPS];
#pragma unroll
    for (int t = 0; t < T_STEPS; ++t)
      sv[t] = cur3[(size_t)(t * NITEM + item) * NPAD + n];
    float mem = 0.f, cnt = 0.f;
    int first = -1;
#pragma unroll
    for (int t = 0; t < T_STEPS; ++t) {
      float r = (mem > THR) ? 1.f : 0.f;
      mem = BETA * mem + (bias + sv[t]) - r;
      if (mem > THR) { cnt += 1.f; if (first < 0) first = t; }
    }
    cr[n] = cnt;
    cr[NFC + n] = (first < 0) ? 0.f : ((float)first / (float)T_STEPS);
  }
  __syncthreads();
  int o = threadIdx.x;
  float acc = 0.f;
  if (o < 128) {
    acc = fcsb[o];
    const float4* w4 = reinterpret_cast<const float4*>(fcsw + o * 500);
#pragma unroll 5
    for (int j4 = 0; j4 < 125; ++j4) {
      float4 wv = w4[j4];
      acc += cr[4 * j4 + 0] * wv.x;
      acc += cr[4 * j4 + 1] * wv.y;
      acc += cr[4 * j4 + 2] * wv.z;
      acc += cr[4 * j4 + 3] * wv.w;
    }
    float sq = acc * acc;
    for (int off = 32; off > 0; off >>= 1) sq += __shfl_down(sq, off, 64);
    if ((o & 63) == 0) red[o >> 6] = sq;
  }
  __syncthreads();
  if (o < 128) {
    float norm = sqrtf(red[0] + red[1]);
    norm = fmaxf(norm, 1e-12f);
    dout[item * 128 + o] = acc / norm;
  }
}

// ---------------- launch ----------------
extern "C" void kernel_launch(void* const* d_in, const int* in_sizes, int n_in,
                              void* d_out, int out_size, void* d_ws, size_t ws_size,
                              hipStream_t stream) {
  const float* x1   = (const float*)d_in[0];
  const float* x2   = (const float*)d_in[1];
  const float* c1w  = (const float*)d_in[2];
  const float* c1b  = (const float*)d_in[3];
  const float* bn1g = (const float*)d_in[4];
  const float* bn1b = (const float*)d_in[5];
  const float* bn1m = (const float*)d_in[6];
  const float* bn1v = (const float*)d_in[7];
  const float* c2w  = (const float*)d_in[8];
  const float* c2b  = (const float*)d_in[9];
  const float* bn2g = (const float*)d_in[10];
  const float* bn2b = (const float*)d_in[11];
  const float* bn2m = (const float*)d_in[12];
  const float* bn2v = (const float*)d_in[13];
  const float* fc1w = (const float*)d_in[14];
  const float* fc1b = (const float*)d_in[15];
  const float* fcsw = (const float*)d_in[16];
  const float* fcsb = (const float*)d_in[17];

  char* ws = (char*)d_ws;
  float*    cur3    = (float*)(ws + OFF_CUR1 + OFF_CUR3);
  uint8_t*  pooledT = (uint8_t*)(ws + OFF_POOL);
  uint8_t*  spk2    = (uint8_t*)(ws + OFF_SPK2);
  uint8_t*  wTf     = (uint8_t*)(ws + OFF_WT);

  hipMemsetAsync(cur3, 0, (size_t)MROWS * NPAD * sizeof(float), stream);
  k_pre<<<dim3(NKTILE + 8 * NITEM), dim3(256), 0, stream>>>(fc1w, wTf, x1, x2, c1w, c1b,
                                                            bn1g, bn1b, bn1m, bn1v, pooledT);
  k_conv2<<<dim3(8, NITEM), dim3(256), 0, stream>>>(pooledT, c2w, c2b, bn2g, bn2b, bn2m, bn2v,
                                                    (uint32_t*)spk2);
  k_fc1<<<dim3(KSPLIT, T_STEPS / 2), dim3(512), 0, stream>>>(spk2, wTf, cur3);
  k_tail<<<dim3(NITEM), dim3(256), 0, stream>>>(cur3, fc1b, fcsw, fcsb, (float*)d_out);
}

// Round 20
// 169.455 us; speedup vs baseline: 1.1162x; 1.1162x over previous
//
#include <hip/hip_runtime.h>
#include <math.h>
#include <stdint.h>

// ---------------- dims ----------------
#define BETA 0.9f
#define THR 1.0f
#define T_STEPS 50
#define BN_EPS 1e-5f

#define NITEM 64          // 2 inputs x 32 batch
#define C1 16
#define L1 1981           // conv1 out length
#define P4 495            // pooled length
#define C2 32
#define L2 493            // conv2 out length
#define L2PAD 496
#define KTOT 15872        // C2*L2PAD (padded flat dim)
#define KREAL 15776       // C2*L2
#define NFC 250
#define NPAD 256
#define KSPLIT 16
#define KRANGE 992        // KTOT/KSPLIT
#define KSTEPS 31         // KRANGE/32
#define NKTILE 496        // KTOT/32
#define MROWS 3200        // T_STEPS*NITEM
#define TSLICE 1015808    // KTOT*64 bytes per t (blocked spk2 slice)

// ---------------- workspace layout (bytes) ----------------
#define OFF_CUR1 0UL
#define OFF_POOL 8126464UL            // (pooledT; REUSED as part slices 8..15 after conv2)
#define OFF_SPK2 34340864UL           // spk2 blocked = 50*TSLICE
#define OFF_WT   85131264UL           // wTf
#define OFF_PART 101384192UL          // part slices 0..7
// cur1 region is pure scratch: cur3 at +16384
#define OFF_CUR3 16384UL

typedef __attribute__((ext_vector_type(8))) short bf16x8;
typedef __attribute__((ext_vector_type(4))) float f32x4;

__device__ __forceinline__ uint32_t f32_to_bf16_rne(float f) {
  uint32_t u = __float_as_uint(f);
  return (u + 0x7FFFu + ((u >> 16) & 1u)) >> 16;
}

// spike bytes (bit0) -> 8 bf16 {0,1} in PERMUTED k-order [0,2,1,3,4,6,5,7]
// (B operands are packed in the same order, so the MFMA dot product is unchanged)
__device__ __forceinline__ bf16x8 frag_from_bytes(uint2 a) {
  union { uint32_t u[4]; bf16x8 v; } c;
  c.u[0] = (a.x & 0x00010001u) * 0x3F80u;          // k0,k2
  c.u[1] = ((a.x >> 8) & 0x00010001u) * 0x3F80u;   // k1,k3
  c.u[2] = (a.y & 0x00010001u) * 0x3F80u;          // k4,k6
  c.u[3] = ((a.y >> 8) & 0x00010001u) * 0x3F80u;   // k5,k7
  return c.v;
}

// ---------------- K_pre: MERGED independent prep ----------------
// blocks [0, 496): k_wt  -- fc1w -> wTf fragment-ready bf16 hi/lo (permuted k-pairs)
// blocks [496, 1008): conv1+BN1 (LDS) + LIF1 + maxpool4 -> pooledT (x hoisted to registers)
__global__ __launch_bounds__(256) void k_pre(const float* __restrict__ fc1w,
                                             uint8_t* __restrict__ wTf,
                                             const float* __restrict__ x1, const float* __restrict__ x2,
                                             const float* __restrict__ c1w, const float* __restrict__ c1b,
                                             const float* __restrict__ g, const float* __restrict__ bb,
                                             const float* __restrict__ mn, const float* __restrict__ vr,
                                             uint8_t* __restrict__ pooledT) {
  __shared__ __align__(16) union SM {
    float ftile[256][33];                                  // wt branch (33.8 KB)
    struct { float xs[1104]; float cur_l[16][260]; } c;    // conv branch (21.1 KB)
  } sm;
  int bid = blockIdx.x;
  int tid = threadIdx.x;

  if (bid < NKTILE) {
    // ----- k_wt body (kt = bid) -----
    int kt = bid;
    {
      int kk = tid & 31;
      int r8 = tid >> 5;
      int k = kt * 32 + kk;
      int oc = k / L2PAD;
      int pos = k - oc * L2PAD;
      bool kvalid = (pos < L2);
      size_t src = (size_t)oc * L2 + pos;
#pragma unroll
      for (int p = 0; p < 32; ++p) {
        int n = p * 8 + r8;
        float w = 0.f;
        if (kvalid && n < NFC) w = fc1w[(size_t)n * KREAL + src];
        sm.ftile[n][kk] = w;
      }
    }
    __syncthreads();
    int n = tid;
    int wv = n >> 6, ni = (n >> 4) & 3, r16 = n & 15;
    uint32_t h16[32], l16[32];
#pragma unroll
    for (int kl = 0; kl < 32; ++kl) {
      float w = sm.ftile[n][kl];
      uint32_t hb = f32_to_bf16_rne(w);
      float hf = __uint_as_float(hb << 16);
      h16[kl] = hb;
      l16[kl] = f32_to_bf16_rne(w - hf);
    }
    uint8_t* tb = wTf + (size_t)kt * 32768 + wv * 8192 + ni * 2048;
#pragma unroll
    for (int gq = 0; gq < 4; ++gq) {
      int b = gq * 8;
      uint4 h;
      h.x = h16[b + 0] | (h16[b + 2] << 16);
      h.y = h16[b + 1] | (h16[b + 3] << 16);
      h.z = h16[b + 4] | (h16[b + 6] << 16);
      h.w = h16[b + 5] | (h16[b + 7] << 16);
      *reinterpret_cast<uint4*>(tb + (gq * 16 + r16) * 16) = h;
      uint4 l;
      l.x = l16[b + 0] | (l16[b + 2] << 16);
      l.y = l16[b + 1] | (l16[b + 3] << 16);
      l.z = l16[b + 4] | (l16[b + 6] << 16);
      l.w = l16[b + 5] | (l16[b + 7] << 16);
      *reinterpret_cast<uint4*>(tb + 1024 + (gq * 16 + r16) * 16) = l;
    }
  } else {
    // ----- conv1+LIF1 body -----
    int b = bid - NKTILE;
    int pc = b & 7;
    int item = b >> 3;
    const float* x = (item < 32 ? x1 : x2) + (item & 31) * 8000;
    int xoff = pc * 1024;
    for (int i = tid; i < 1100; i += 256) {
      int gi = xoff + i;
      sm.c.xs[i] = (gi < 8000) ? x[gi] : 0.f;
    }
    __syncthreads();
    const float4* xs4 = reinterpret_cast<const float4*>(sm.c.xs);
    float4 xv[20];
#pragma unroll
    for (int k4 = 0; k4 < 20; ++k4) xv[k4] = xs4[tid + k4];   // channel-invariant: load ONCE
    for (int c = 0; c < C1; ++c) {
      float s = g[c] / sqrtf(vr[c] + BN_EPS);
      float sh = (c1b[c] - mn[c]) * s + bb[c];
      const float4* w4 = reinterpret_cast<const float4*>(c1w + c * 80);
      float acc = 0.f;
#pragma unroll
      for (int k4 = 0; k4 < 20; ++k4) {
        float4 wv4 = w4[k4];
        acc += wv4.x * xv[k4].x; acc += wv4.y * xv[k4].y;
        acc += wv4.z * xv[k4].z; acc += wv4.w * xv[k4].w;
      }
      sm.c.cur_l[c][tid] = acc * s + sh;
    }
    __syncthreads();
    int gq = tid & 3;
    int p4l = tid >> 2;
    int p4 = pc * 64 + p4l;
    if (p4 >= P4) return;
    float4 cv[4];
#pragma unroll
    for (int j = 0; j < 4; ++j)
      cv[j] = *reinterpret_cast<const float4*>(&sm.c.cur_l[gq * 4 + j][4 * p4l]);
    float m[4][4];
#pragma unroll
    for (int j = 0; j < 4; ++j)
#pragma unroll
      for (int r = 0; r < 4; ++r) m[j][r] = 0.f;
    uint32_t* out = reinterpret_cast<uint32_t*>(pooledT + ((size_t)item * 50 * 512 + p4) * 16 + gq * 4);
    for (int t = 0; t < T_STEPS; ++t) {
      uint32_t pk = 0;
#pragma unroll
      for (int j = 0; j < 4; ++j) {
        int s = 0;
#pragma unroll
        for (int r = 0; r < 4; ++r) {
          float rst = (m[j][r] > THR) ? 1.f : 0.f;
          float cvv = (r == 0) ? cv[j].x : (r == 1) ? cv[j].y : (r == 2) ? cv[j].z : cv[j].w;
          m[j][r] = BETA * m[j][r] + cvv - rst;
          s |= (m[j][r] > THR);
        }
        pk |= ((uint32_t)s) << (8 * j);
      }
      out[t * 2048] = pk;
    }
  }
}

// ---------------- K4: conv2 via MFMA + LIF2, inline weight frags -> spk2 BLOCKED [t][kchunk][item][32B] ----------------
__global__ __launch_bounds__(256) void k_conv2(const uint8_t* __restrict__ pooledT,
                                               const float* __restrict__ c2w, const float* __restrict__ c2b,
                                               const float* __restrict__ g, const float* __restrict__ bb,
                                               const float* __restrict__ mn, const float* __restrict__ vr,
                                               uint32_t* __restrict__ spk2) {
  int item = blockIdx.y;
  int pt = blockIdx.x;
  int tid = threadIdx.x;
  int lane = tid & 63, wv = tid >> 6;
  int r16 = lane & 15, kg = lane >> 4;
  bf16x8 bw[2][2][2];
  float sh[2];
#pragma unroll
  for (int nt = 0; nt < 2; ++nt) {
    int oc = nt * 16 + r16;
    float s2 = g[oc] * rsqrtf(vr[oc] + BN_EPS);
    sh[nt] = (c2b[oc] - mn[oc]) * s2 + bb[oc];
#pragma unroll
    for (int kt = 0; kt < 2; ++kt) {
      uint32_t h[8], l[8];
#pragma unroll
      for (int j = 0; j < 8; ++j) {
        int k = kt * 32 + kg * 8 + j;
        int tap = k >> 4, ic = k & 15;
        float raw = (tap < 3) ? c2w[oc * 48 + ic * 3 + tap] * s2 : 0.f;
        uint32_t hb = f32_to_bf16_rne(raw);
        float hf = __uint_as_float(hb << 16);
        h[j] = hb;
        l[j] = f32_to_bf16_rne(raw - hf);
      }
      union { uint32_t u[4]; bf16x8 v; } ch_, cl_;
      ch_.u[0] = h[0] | (h[2] << 16); ch_.u[1] = h[1] | (h[3] << 16);
      ch_.u[2] = h[4] | (h[6] << 16); ch_.u[3] = h[5] | (h[7] << 16);
      cl_.u[0] = l[0] | (l[2] << 16); cl_.u[1] = l[1] | (l[3] << 16);
      cl_.u[2] = l[4] | (l[6] << 16); cl_.u[3] = l[5] | (l[7] << 16);
      bw[nt][kt][0] = ch_.v;
      bw[nt][kt][1] = cl_.v;
    }
  }
  const uint8_t* base = pooledT + (size_t)item * 50 * 8192;
  int rowA = pt * 64 + wv * 16 + r16;
  size_t off0 = (size_t)(rowA + (kg >> 1)) * 16 + 8 * (kg & 1);   // taps 0/1
  size_t off1 = (size_t)(rowA + 2) * 16 + 8 * (kg & 1);           // tap 2 (+pad)
  uint2 na0 = *reinterpret_cast<const uint2*>(base + off0);
  uint2 na1 = *reinterpret_cast<const uint2*>(base + off1);
  float mem[2][4] = {{0.f, 0.f, 0.f, 0.f}, {0.f, 0.f, 0.f, 0.f}};
  int pos_base = pt * 64 + wv * 16 + kg * 4;
  bool dostore = pos_base < L2PAD;
  int k0a = r16 * L2PAD + pos_base;
  int k0b = (16 + r16) * L2PAD + pos_base;
  uint32_t sidx0 = (uint32_t)(k0a >> 5) * 512u + (uint32_t)item * 8u + ((uint32_t)(k0a >> 2) & 7u);
  uint32_t sidx1 = (uint32_t)(k0b >> 5) * 512u + (uint32_t)item * 8u + ((uint32_t)(k0b >> 2) & 7u);
  for (int t = 0; t < T_STEPS; ++t) {
    uint2 a0 = na0, a1 = na1;
    const uint8_t* nb = base + (size_t)((t + 1 < T_STEPS) ? t + 1 : t) * 8192;
    na0 = *reinterpret_cast<const uint2*>(nb + off0);
    na1 = *reinterpret_cast<const uint2*>(nb + off1);
    bf16x8 af0 = frag_from_bytes(a0);
    bf16x8 af1 = frag_from_bytes(a1);
    uint32_t st[2];
#pragma unroll
    for (int nt = 0; nt < 2; ++nt) {
      f32x4 acc = (f32x4){0.f, 0.f, 0.f, 0.f};
      acc = __builtin_amdgcn_mfma_f32_16x16x32_bf16(af0, bw[nt][0][0], acc, 0, 0, 0);
      acc = __builtin_amdgcn_mfma_f32_16x16x32_bf16(af1, bw[nt][1][0], acc, 0, 0, 0);
      acc = __builtin_amdgcn_mfma_f32_16x16x32_bf16(af0, bw[nt][0][1], acc, 0, 0, 0);
      acc = __builtin_amdgcn_mfma_f32_16x16x32_bf16(af1, bw[nt][1][1], acc, 0, 0, 0);
      uint32_t packed = 0;
#pragma unroll
      for (int r = 0; r < 4; ++r) {
        float rst = (mem[nt][r] > THR) ? 1.f : 0.f;
        mem[nt][r] = BETA * mem[nt][r] + (acc[r] + sh[nt]) - rst;
        packed |= (mem[nt][r] > THR ? 1u : 0u) << (8 * r);
      }
      st[nt] = packed;
    }
    if (dostore) {
      uint32_t tb = (uint32_t)t * (TSLICE / 4);
      spk2[tb + sidx0] = st[0];
      spk2[tb + sidx1] = st[1];
    }
  }
}

// ---------------- K5: fc1 MFMA GEMM, LDS-free, blocked-A, M=128 via 8 waves (R8 best) ----------------
__global__ __launch_bounds__(512) void k_fc1(const uint8_t* __restrict__ spk2,
                                             const uint8_t* __restrict__ wTf,
                                             float* __restrict__ part0,
                                             float* __restrict__ part1) {
  int ks = blockIdx.x;       // 0..15
  int mt = blockIdx.y;       // 0..24
  int tid = threadIdx.x;
  int lane = tid & 63, w8 = tid >> 6;
  int wv = w8 & 3, mg = w8 >> 2;
  int r16 = lane & 15, kg = lane >> 4;
  int t = mt * 2 + mg;

  f32x4 acc[4][4];
#pragma unroll
  for (int mi = 0; mi < 4; ++mi)
#pragma unroll
    for (int ni = 0; ni < 4; ++ni) acc[mi][ni] = (f32x4){0.f, 0.f, 0.f, 0.f};

  const uint8_t* abase = spk2 + (size_t)t * TSLICE + (size_t)(ks * KSTEPS) * 2048 + r16 * 32 + kg * 8;
  const uint8_t* bbase = wTf + (size_t)ks * KSTEPS * 32768 + wv * 8192 + lane * 16;

  for (int ch = 0; ch < KSTEPS; ++ch) {
    uint2 a[4];
#pragma unroll
    for (int mi = 0; mi < 4; ++mi)
      a[mi] = *reinterpret_cast<const uint2*>(abase + (size_t)ch * 2048 + mi * 512);
    bf16x8 bfr[4][2];
#pragma unroll
    for (int ni = 0; ni < 4; ++ni)
#pragma unroll
      for (int sel = 0; sel < 2; ++sel)
        bfr[ni][sel] = *reinterpret_cast<const bf16x8*>(bbase + (size_t)ch * 32768 + ni * 2048 + sel * 1024);
    bf16x8 af[4];
#pragma unroll
    for (int mi = 0; mi < 4; ++mi) af[mi] = frag_from_bytes(a[mi]);
#pragma unroll
    for (int ni = 0; ni < 4; ++ni)
#pragma unroll
      for (int mi = 0; mi < 4; ++mi) {
        acc[mi][ni] = __builtin_amdgcn_mfma_f32_16x16x32_bf16(af[mi], bfr[ni][0], acc[mi][ni], 0, 0, 0);
        acc[mi][ni] = __builtin_amdgcn_mfma_f32_16x16x32_bf16(af[mi], bfr[ni][1], acc[mi][ni], 0, 0, 0);
      }
  }
  float* pb = (ks < 8) ? (part0 + (size_t)ks * MROWS * NPAD)
                       : (part1 + (size_t)(ks - 8) * MROWS * NPAD);
  int colb = wv * 64 + r16;
  int rowb = t * 64 + kg * 4;
#pragma unroll
  for (int mi = 0; mi < 4; ++mi)
#pragma unroll
    for (int ni = 0; ni < 4; ++ni) {
      float* pp = pb + (size_t)(rowb + mi * 16) * NPAD + colb + ni * 16;
#pragma unroll
      for (int r = 0; r < 4; ++r) pp[r * NPAD] = acc[mi][ni][r];
    }
}

// ---------------- K6a: reduce 16 K-splits (float4) -> cur3[3200][256] ----------------
__global__ __launch_bounds__(256) void k_red(const float* __restrict__ part0,
                                             const float* __restrict__ part1,
                                             float* __restrict__ cur3) {
  int i4 = blockIdx.x * 256 + threadIdx.x;          // 0..204799 float4s
  const float4* p0 = reinterpret_cast<const float4*>(part0);
  const float4* p1 = reinterpret_cast<const float4*>(part1);
  const size_t sl4 = (size_t)MROWS * NPAD / 4;
  float4 s = p0[i4];
#pragma unroll
  for (int ksx = 1; ksx < 8; ++ksx) {
    float4 v = p0[ksx * sl4 + i4];
    s.x += v.x; s.y += v.y; s.z += v.z; s.w += v.w;
  }
#pragma unroll
  for (int ksx = 0; ksx < 8; ++ksx) {
    float4 v = p1[ksx * sl4 + i4];
    s.x += v.x; s.y += v.y; s.z += v.z; s.w += v.w;
  }
  reinterpret_cast<float4*>(cur3)[i4] = s;
}

// ---------------- K6b: FUSED LIF3 + head GEMM + L2 normalize -> d_out ----------------
__global__ __launch_bounds__(256) void k_tail(const float* __restrict__ cur3,
                                              const float* __restrict__ fc1b,
                                              const float* __restrict__ fcsw,
                                              const float* __restrict__ fcsb,
                                              float* __restrict__ dout) {
  __shared__ float cr[500];
  __shared__ float red[2];
  int item = blockIdx.x;
  int n = threadIdx.x;
  if (n < NFC) {
    float bias = fc1b[n];
    float sv[T_STEPS];
#pragma unroll
    for (int t = 0; t < T_STEPS; ++t)
      sv[t] = cur3[(size_t)(t * NITEM + item) * NPAD + n];
    float mem = 0.f, cnt = 0.f;
    int first = -1;
#pragma unroll
    for (int t = 0; t < T_STEPS; ++t) {
      float r = (mem > THR) ? 1.f : 0.f;
      mem = BETA * mem + (bias + sv[t]) - r;
      if (mem > THR) { cnt += 1.f; if (first < 0) first = t; }
    }
    cr[n] = cnt;
    cr[NFC + n] = (first < 0) ? 0.f : ((float)first / (float)T_STEPS);
  }
  __syncthreads();
  int o = threadIdx.x;
  float acc = 0.f;
  if (o < 128) {
    acc = fcsb[o];
    const float4* w4 = reinterpret_cast<const float4*>(fcsw + o * 500);
#pragma unroll 5
    for (int j4 = 0; j4 < 125; ++j4) {
      float4 wv = w4[j4];
      acc += cr[4 * j4 + 0] * wv.x;
      acc += cr[4 * j4 + 1] * wv.y;
      acc += cr[4 * j4 + 2] * wv.z;
      acc += cr[4 * j4 + 3] * wv.w;
    }
    float sq = acc * acc;
    for (int off = 32; off > 0; off >>= 1) sq += __shfl_down(sq, off, 64);
    if ((o & 63) == 0) red[o >> 6] = sq;
  }
  __syncthreads();
  if (o < 128) {
    float norm = sqrtf(red[0] + red[1]);
    norm = fmaxf(norm, 1e-12f);
    dout[item * 128 + o] = acc / norm;
  }
}

// ---------------- launch ----------------
extern "C" void kernel_launch(void* const* d_in, const int* in_sizes, int n_in,
                              void* d_out, int out_size, void* d_ws, size_t ws_size,
                              hipStream_t stream) {
  const float* x1   = (const float*)d_in[0];
  const float* x2   = (const float*)d_in[1];
  const float* c1w  = (const float*)d_in[2];
  const float* c1b  = (const float*)d_in[3];
  const float* bn1g = (const float*)d_in[4];
  const float* bn1b = (const float*)d_in[5];
  const float* bn1m = (const float*)d_in[6];
  const float* bn1v = (const float*)d_in[7];
  const float* c2w  = (const float*)d_in[8];
  const float* c2b  = (const float*)d_in[9];
  const float* bn2g = (const float*)d_in[10];
  const float* bn2b = (const float*)d_in[11];
  const float* bn2m = (const float*)d_in[12];
  const float* bn2v = (const float*)d_in[13];
  const float* fc1w = (const float*)d_in[14];
  const float* fc1b = (const float*)d_in[15];
  const float* fcsw = (const float*)d_in[16];
  const float* fcsb = (const float*)d_in[17];

  char* ws = (char*)d_ws;
  float*    cur3    = (float*)(ws + OFF_CUR1 + OFF_CUR3);
  uint8_t*  pooledT = (uint8_t*)(ws + OFF_POOL);
  float*    part1   = (float*)(ws + OFF_POOL);            // reused AFTER k_conv2 (slices 8..15)
  uint8_t*  spk2    = (uint8_t*)(ws + OFF_SPK2);
  uint8_t*  wTf     = (uint8_t*)(ws + OFF_WT);
  float*    part0   = (float*)(ws + OFF_PART);

  k_pre<<<dim3(NKTILE + 8 * NITEM), dim3(256), 0, stream>>>(fc1w, wTf, x1, x2, c1w, c1b,
                                                            bn1g, bn1b, bn1m, bn1v, pooledT);
  k_conv2<<<dim3(8, NITEM), dim3(256), 0, stream>>>(pooledT, c2w, c2b, bn2g, bn2b, bn2m, bn2v,
                                                    (uint32_t*)spk2);
  k_fc1<<<dim3(KSPLIT, T_STEPS / 2), dim3(512), 0, stream>>>(spk2, wTf, part0, part1);
  k_red<<<dim3(MROWS * NPAD / 1024), dim3(256), 0, stream>>>(part0, part1, cur3);
  k_tail<<<dim3(NITEM), dim3(256), 0, stream>>>(cur3, fc1b, fcsw, fcsb, (float*)d_out);
}